// Round 4
// baseline (423.478 us; speedup 1.0000x reference)
//
#include <hip/hip_runtime.h>

typedef unsigned short u16;
typedef __bf16 bf16x8 __attribute__((ext_vector_type(8)));
typedef float f32x4 __attribute__((ext_vector_type(4)));
typedef unsigned short us8 __attribute__((ext_vector_type(8)));

#define BB 4
#define TT 4096
#define HID 1024
#define NH 16
#define HD 64
#define BT (BB*TT)          // 16384 rows
#define NCH 128             // chunks over T
#define LOG_NCH 7
#define CLEN (TT/NCH)       // 32

__device__ __forceinline__ float bf2f(u16 u) {
    return __uint_as_float(((unsigned)u) << 16);
}
__device__ __forceinline__ u16 f2bf(float f) {
    unsigned u = __float_as_uint(f);
    unsigned r = 0x7FFFu + ((u >> 16) & 1u);
    return (u16)((u + r) >> 16);
}
__device__ __forceinline__ float phi(float x) {      // elu(x)+1
    return x > 0.f ? x + 1.f : __expf(x);
}
__device__ __forceinline__ float sigmoidf(float x) {
    return 1.f / (1.f + __expf(-x));
}
__device__ __forceinline__ float4 u4_to_f4(ushort4 u) {
    return make_float4(bf2f(u.x), bf2f(u.y), bf2f(u.z), bf2f(u.w));
}

// ---------------- fused fp32 -> bf16 convert (one launch for all 4 tensors) ----------
#define CN1 (BT*HID/4)          // x      : 4194304
#define CN2 (3*HID*HID/4)       // Wqkv   :  786432
#define CN3 (HID*HID/4)         // Wgate  :  262144
#define CN4 (HID*HID/4)         // Wout   :  262144
__global__ void convert_all(const float4* __restrict__ x,    const float4* __restrict__ wqkv,
                            const float4* __restrict__ wgate, const float4* __restrict__ wout,
                            ushort4* __restrict__ xb,    ushort4* __restrict__ wqkvb,
                            ushort4* __restrict__ wgateb, ushort4* __restrict__ woutb) {
    int i = blockIdx.x * 256 + threadIdx.x;
    const float4* src; ushort4* dst; int j;
    if (i < CN1)                 { src = x;     dst = xb;     j = i; }
    else if (i < CN1+CN2)        { src = wqkv;  dst = wqkvb;  j = i - CN1; }
    else if (i < CN1+CN2+CN3)    { src = wgate; dst = wgateb; j = i - CN1 - CN2; }
    else                         { src = wout;  dst = woutb;  j = i - CN1 - CN2 - CN3; }
    float4 f = src[j];
    ushort4 u;
    u.x = f2bf(f.x); u.y = f2bf(f.y); u.z = f2bf(f.z); u.w = f2bf(f.w);
    dst[j] = u;
}

// ---------------- MFMA GEMM: C[M,N] = A[M,K] @ W[N,K]^T (both K-major bf16) ---------
// 128x128 tile, BK=64, 4 waves. XOR-swizzled LDS (verified: 0 bank conflicts).
// XCD-aware block remap: XCD x owns a contiguous M-stripe (A slice = 4 MB = one L2).
// Epilogue: C-tile via LDS (32-row slabs) -> coalesced ushort8 stores.
__global__ __launch_bounds__(256)
void gemm_bt(const u16* __restrict__ A, const u16* __restrict__ Bm,
             int M, int N, int K, u16* __restrict__ Cout)
{
    __shared__ u16 As[128 * 64];
    __shared__ u16 Bs[128 * 64];
    const int tid  = threadIdx.x;
    const int wave = tid >> 6;
    const int lane = tid & 63;

    // XCD swizzle (assumes XCD = linear_block_id % 8; any bijection is correct)
    const int lin   = blockIdx.y * gridDim.x + blockIdx.x;
    const int xcd   = lin & 7;
    const int seq   = lin >> 3;
    const int bands = gridDim.y >> 3;           // row-bands per XCD
    const int my_by = xcd * bands + (seq % bands);
    const int my_bx = seq / bands;
    const int m0 = my_by * 128;
    const int n0 = my_bx * 128;

    const int mw = (wave & 1) * 64;
    const int nw = (wave >> 1) * 64;
    const int r16 = lane & 15;
    const int q4  = (lane >> 4) * 4;

    f32x4 acc[4][4];
    #pragma unroll
    for (int i = 0; i < 4; ++i)
        #pragma unroll
        for (int j = 0; j < 4; ++j)
            acc[i][j] = (f32x4){0.f, 0.f, 0.f, 0.f};

    for (int k0 = 0; k0 < K; k0 += 64) {
        #pragma unroll
        for (int i = 0; i < 4; ++i) {
            int s   = i * 4 + wave;          // segment 0..15 (wave-uniform)
            int idx = s * 64 + lane;         // linear 16B-chunk index
            int pr  = idx >> 3;
            int pc  = idx & 7;
            int lc  = pc ^ (pr & 7);         // XOR swizzle
            const u16* gA = A  + (size_t)(m0 + pr) * K + k0 + lc * 8;
            const u16* gB = Bm + (size_t)(n0 + pr) * K + k0 + lc * 8;
            __builtin_amdgcn_global_load_lds(
                (const __attribute__((address_space(1))) void*)gA,
                (__attribute__((address_space(3))) void*)&As[s * 512], 16, 0, 0);
            __builtin_amdgcn_global_load_lds(
                (const __attribute__((address_space(1))) void*)gB,
                (__attribute__((address_space(3))) void*)&Bs[s * 512], 16, 0, 0);
        }
        __syncthreads();
        #pragma unroll
        for (int s2 = 0; s2 < 2; ++s2) {
            const int lcq = s2 * 4 + (lane >> 4);
            const int pcq = lcq ^ (r16 & 7);
            bf16x8 af[4], bq[4];
            #pragma unroll
            for (int i = 0; i < 4; ++i)
                af[i] = *(const bf16x8*)&As[(mw + i * 16 + r16) * 64 + pcq * 8];
            #pragma unroll
            for (int j = 0; j < 4; ++j)
                bq[j] = *(const bf16x8*)&Bs[(nw + j * 16 + r16) * 64 + pcq * 8];
            #pragma unroll
            for (int i = 0; i < 4; ++i)
                #pragma unroll
                for (int j = 0; j < 4; ++j)
                    acc[i][j] = __builtin_amdgcn_mfma_f32_16x16x32_bf16(af[i], bq[j], acc[i][j], 0, 0, 0);
        }
        __syncthreads();
    }

    // ---- epilogue: 4 slabs of 32 rows through LDS, coalesced ushort8 stores ----
    float* Cs = (float*)As;                     // 32*128*4 = 16 KB
    #pragma unroll
    for (int slab = 0; slab < 4; ++slab) {
        if ((mw == 64) == (slab >= 2)) {        // this wave owns slab's rows
            int i0 = (slab & 1) * 2;
            #pragma unroll
            for (int ii = 0; ii < 2; ++ii) {
                #pragma unroll
                for (int j = 0; j < 4; ++j) {
                    int col = nw + j * 16 + r16;
                    #pragma unroll
                    for (int r = 0; r < 4; ++r)
                        Cs[(ii * 16 + q4 + r) * 128 + col] = acc[i0 + ii][j][r];
                }
            }
        }
        __syncthreads();
        #pragma unroll
        for (int s = 0; s < 2; ++s) {
            int g   = s * 256 + tid;
            int row = g >> 4;
            int cg  = g & 15;
            const float* cp = &Cs[row * 128 + cg * 8];
            us8 o;
            #pragma unroll
            for (int e = 0; e < 8; ++e) o[e] = f2bf(cp[e]);
            size_t grow = (size_t)(m0 + slab * 32 + row);
            *(us8*)&Cout[grow * N + n0 + cg * 8] = o;
        }
        __syncthreads();
    }
}

// ---------------- small-tile MFMA GEMM: 64x128 tile, for N=1024 GEMMs ---------------
// EPI 1: gate epilogue (bf16 out). EPI 2: fp32 out. LDS-staged vectorized epilogue.
template<int EPI>
__global__ __launch_bounds__(256)
void gemm_bt_sm(const u16* __restrict__ A, const u16* __restrict__ Bm,
                int M, int N, int K, void* __restrict__ Cout,
                const float* __restrict__ bg,
                const u16* __restrict__ attn,
                const u16* __restrict__ qkv)
{
    __shared__ u16 As[64 * 64];
    __shared__ u16 Bs[128 * 64];
    const int tid  = threadIdx.x;
    const int wave = tid >> 6;
    const int lane = tid & 63;

    // XCD swizzle: XCD x owns 32 consecutive row-bands (A slice = 4 MB = one L2)
    const int lin   = blockIdx.y * gridDim.x + blockIdx.x;
    const int xcd   = lin & 7;
    const int seq   = lin >> 3;
    const int bands = gridDim.y >> 3;           // 32
    const int my_by = xcd * bands + (seq % bands);
    const int my_bx = seq / bands;
    const int m0 = my_by * 64;
    const int n0 = my_bx * 128;

    const int mw = (wave & 1) * 32;
    const int nw = (wave >> 1) * 64;
    const int r16 = lane & 15;
    const int q4  = (lane >> 4) * 4;

    f32x4 acc[2][4];
    #pragma unroll
    for (int i = 0; i < 2; ++i)
        #pragma unroll
        for (int j = 0; j < 4; ++j)
            acc[i][j] = (f32x4){0.f, 0.f, 0.f, 0.f};

    for (int k0 = 0; k0 < K; k0 += 64) {
        #pragma unroll
        for (int i = 0; i < 4; ++i) {
            int s   = i * 4 + wave;          // B segment 0..15
            int idx = s * 64 + lane;
            int pr  = idx >> 3;
            int pc  = idx & 7;
            int lc  = pc ^ (pr & 7);
            const u16* gB = Bm + (size_t)(n0 + pr) * K + k0 + lc * 8;
            __builtin_amdgcn_global_load_lds(
                (const __attribute__((address_space(1))) void*)gB,
                (__attribute__((address_space(3))) void*)&Bs[s * 512], 16, 0, 0);
            if (i < 2) {                     // A segments 0..7 (64 rows)
                const u16* gA = A + (size_t)(m0 + pr) * K + k0 + lc * 8;
                __builtin_amdgcn_global_load_lds(
                    (const __attribute__((address_space(1))) void*)gA,
                    (__attribute__((address_space(3))) void*)&As[s * 512], 16, 0, 0);
            }
        }
        __syncthreads();
        #pragma unroll
        for (int s2 = 0; s2 < 2; ++s2) {
            const int lcq = s2 * 4 + (lane >> 4);
            const int pcq = lcq ^ (r16 & 7);
            bf16x8 af[2], bq[4];
            #pragma unroll
            for (int i = 0; i < 2; ++i)
                af[i] = *(const bf16x8*)&As[(mw + i * 16 + r16) * 64 + pcq * 8];
            #pragma unroll
            for (int j = 0; j < 4; ++j)
                bq[j] = *(const bf16x8*)&Bs[(nw + j * 16 + r16) * 64 + pcq * 8];
            #pragma unroll
            for (int i = 0; i < 2; ++i)
                #pragma unroll
                for (int j = 0; j < 4; ++j)
                    acc[i][j] = __builtin_amdgcn_mfma_f32_16x16x32_bf16(af[i], bq[j], acc[i][j], 0, 0, 0);
        }
        __syncthreads();
    }

    // ---- epilogue: 2 slabs of 32 rows through LDS, coalesced vector RMW ----
    float* Cs = (float*)Bs;                     // 16 KB
    #pragma unroll
    for (int slab = 0; slab < 2; ++slab) {
        if ((wave & 1) == slab) {
            #pragma unroll
            for (int i = 0; i < 2; ++i) {
                #pragma unroll
                for (int j = 0; j < 4; ++j) {
                    int col = nw + j * 16 + r16;
                    #pragma unroll
                    for (int r = 0; r < 4; ++r)
                        Cs[(i * 16 + q4 + r) * 128 + col] = acc[i][j][r];
                }
            }
        }
        __syncthreads();
        #pragma unroll
        for (int s = 0; s < 2; ++s) {
            int g   = s * 256 + tid;
            int row = g >> 4;
            int cg  = g & 15;
            const float* cp = &Cs[row * 128 + cg * 8];
            size_t grow = (size_t)(m0 + slab * 32 + row);
            int gcol = n0 + cg * 8;
            if (EPI == 1) {
                us8 a8 = *(const us8*)&attn[grow * HID + gcol];
                us8 v8 = *(const us8*)&qkv[grow * (3 * HID) + 2 * HID + gcol];
                us8 o;
                #pragma unroll
                for (int e = 0; e < 8; ++e) {
                    float gv = sigmoidf(cp[e] + bg[gcol + e]);
                    o[e] = f2bf(gv * bf2f(a8[e]) + (1.f - gv) * bf2f(v8[e]));
                }
                *(us8*)&((u16*)Cout)[grow * HID + gcol] = o;
            } else {
                float4 c0 = *(const float4*)cp;
                float4 c1 = *(const float4*)(cp + 4);
                float* op = &((float*)Cout)[grow * N + gcol];
                *(float4*)op = c0;
                *(float4*)(op + 4) = c1;
            }
        }
        __syncthreads();
    }
}

// ---------------- scan pass A: per-chunk local finals (vectorized x4) --------------
__global__ void scan_finals(const u16* __restrict__ qkv, const float* __restrict__ decay_param,
                            float* __restrict__ ckv, float* __restrict__ cks) {
    int g  = blockIdx.x * 16 + (threadIdx.x >> 4);    // ((b*NH+h)*NCH + c)
    int sl = threadIdx.x & 15;
    int c = g & (NCH - 1);
    int h = (g >> LOG_NCH) & (NH - 1);
    int b = g >> (LOG_NCH + 4);
    float decay = sigmoidf(decay_param[h]);
    const u16* kp = qkv + (size_t)(b * TT + c * CLEN) * (3 * HID) + HID + h * HD + sl * 4;
    float4 skv = make_float4(0.f, 0.f, 0.f, 0.f);
    float4 sks = make_float4(0.f, 0.f, 0.f, 0.f);
    for (int t = 0; t < CLEN; ++t) {
        float4 k = u4_to_f4(*(const ushort4*)kp);
        float4 v = u4_to_f4(*(const ushort4*)(kp + HID));
        k.x = phi(k.x); k.y = phi(k.y); k.z = phi(k.z); k.w = phi(k.w);
        skv.x = decay * skv.x + k.x * v.x;  skv.y = decay * skv.y + k.y * v.y;
        skv.z = decay * skv.z + k.z * v.z;  skv.w = decay * skv.w + k.w * v.w;
        sks.x = decay * sks.x + k.x;        sks.y = decay * sks.y + k.y;
        sks.z = decay * sks.z + k.z;        sks.w = decay * sks.w + k.w;
        kp += 3 * HID;
    }
    *(float4*)(ckv + (size_t)g * 64 + sl * 4) = skv;
    *(float4*)(cks + (size_t)g * 64 + sl * 4) = sks;
}

// ---------------- scan pass B: cross-chunk exclusive prefix (in place) -------------
__global__ void scan_prefix(float* __restrict__ ckv, float* __restrict__ cks,
                            const float* __restrict__ decay_param) {
    int bh = blockIdx.x;
    int h  = bh & (NH - 1);
    int lane = threadIdx.x;
    float decay = sigmoidf(decay_param[h]);
    float dC = powf(decay, (float)CLEN);
    float* pkv = ckv + (size_t)bh * NCH * 64 + lane;
    float* pks = cks + (size_t)bh * NCH * 64 + lane;
    float fkv = 0.f, fks = 0.f;
    for (int c = 0; c < NCH; ++c) {
        float lkv = pkv[c * 64], lks = pks[c * 64];
        pkv[c * 64] = fkv; pks[c * 64] = fks;
        fkv = fkv * dC + lkv;
        fks = fks * dC + lks;
    }
}

// ---------------- scan pass C: apply with init, den-reduce, write attn (x4) --------
__global__ void scan_apply(const u16* __restrict__ qkv, const float* __restrict__ decay_param,
                           const float* __restrict__ ckv, const float* __restrict__ cks,
                           u16* __restrict__ attn) {
    int g  = blockIdx.x * 16 + (threadIdx.x >> 4);
    int sl = threadIdx.x & 15;
    int c = g & (NCH - 1);
    int h = (g >> LOG_NCH) & (NH - 1);
    int b = g >> (LOG_NCH + 4);
    float decay = sigmoidf(decay_param[h]);
    float4 skv = *(const float4*)(ckv + (size_t)g * 64 + sl * 4);
    float4 sks = *(const float4*)(cks + (size_t)g * 64 + sl * 4);
    const u16* qp = qkv + (size_t)(b * TT + c * CLEN) * (3 * HID) + h * HD + sl * 4;
    u16* op = attn + (size_t)(b * TT + c * CLEN) * HID + h * HD + sl * 4;
    for (int t = 0; t < CLEN; ++t) {
        float4 q = u4_to_f4(*(const ushort4*)qp);
        float4 k = u4_to_f4(*(const ushort4*)(qp + HID));
        float4 v = u4_to_f4(*(const ushort4*)(qp + 2 * HID));
        q.x = phi(q.x); q.y = phi(q.y); q.z = phi(q.z); q.w = phi(q.w);
        k.x = phi(k.x); k.y = phi(k.y); k.z = phi(k.z); k.w = phi(k.w);
        skv.x = decay * skv.x + k.x * v.x;  skv.y = decay * skv.y + k.y * v.y;
        skv.z = decay * skv.z + k.z * v.z;  skv.w = decay * skv.w + k.w * v.w;
        sks.x = decay * sks.x + k.x;        sks.y = decay * sks.y + k.y;
        sks.z = decay * sks.z + k.z;        sks.w = decay * sks.w + k.w;
        float s = q.x * sks.x + q.y * sks.y + q.z * sks.z + q.w * sks.w;
        s += __shfl_xor(s, 8);
        s += __shfl_xor(s, 4);
        s += __shfl_xor(s, 2);
        s += __shfl_xor(s, 1);
        float inv = 1.f / fmaxf(s, 1e-6f);
        ushort4 o;
        o.x = f2bf(q.x * skv.x * inv); o.y = f2bf(q.y * skv.y * inv);
        o.z = f2bf(q.z * skv.z * inv); o.w = f2bf(q.w * skv.w * inv);
        *(ushort4*)op = o;
        qp += 3 * HID;
        op += HID;
    }
}

extern "C" void kernel_launch(void* const* d_in, const int* in_sizes, int n_in,
                              void* d_out, int out_size, void* d_ws, size_t ws_size,
                              hipStream_t stream) {
    const float* x     = (const float*)d_in[0];   // [4,4096,1024]
    const float* Wqkv  = (const float*)d_in[1];   // [3072,1024]
    const float* Wout  = (const float*)d_in[2];   // [1024,1024]
    const float* Wgate = (const float*)d_in[3];   // [1024,1024]
    const float* bgate = (const float*)d_in[4];   // [1024]
    const float* decay = (const float*)d_in[5];   // [16]

    // workspace layout (bf16 elements)
    u16* xb     = (u16*)d_ws;                                 // 16384*1024 (aliased as attn later)
    u16* wqkvb  = xb    + (size_t)BT * HID;                   // 3072*1024
    u16* wgateb = wqkvb + (size_t)3 * HID * HID;              // 1024*1024
    u16* woutb  = wgateb + (size_t)HID * HID;                 // 1024*1024
    u16* qkvb   = woutb + (size_t)HID * HID;                  // 16384*3072
    u16* out2b  = qkvb  + (size_t)BT * 3 * HID;               // 16384*1024
    float* ckv  = (float*)(out2b + (size_t)BT * HID);         // 4*16*128*64
    float* cks  = ckv + (size_t)BB * NH * NCH * HD;
    u16* attnb  = xb;  // alias: x dead after GEMM1

    // fused converts (one launch)
    convert_all<<<(CN1 + CN2 + CN3 + CN4) / 256, 256, 0, stream>>>(
        (const float4*)x, (const float4*)Wqkv, (const float4*)Wgate, (const float4*)Wout,
        (ushort4*)xb, (ushort4*)wqkvb, (ushort4*)wgateb, (ushort4*)woutb);

    // GEMM1: qkv = x @ Wqkv^T  -> bf16 [16384,3072]
    gemm_bt<<<dim3(3 * HID / 128, BT / 128), 256, 0, stream>>>(
        xb, wqkvb, BT, 3 * HID, HID, qkvb);

    // decay scans -> attn bf16 [16384,1024]
    scan_finals<<<BB * NH * NCH / 16, 256, 0, stream>>>(qkvb, decay, ckv, cks);
    scan_prefix<<<BB * NH, 64, 0, stream>>>(ckv, cks, decay);
    scan_apply<<<BB * NH * NCH / 16, 256, 0, stream>>>(qkvb, decay, ckv, cks, attnb);

    // GEMM2: gate + blend -> out2 bf16 [16384,1024]
    gemm_bt_sm<1><<<dim3(HID / 128, BT / 64), 256, 0, stream>>>(
        attnb, wgateb, BT, HID, HID, out2b, bgate, attnb, qkvb);

    // GEMM3: final projection -> fp32 d_out
    gemm_bt_sm<2><<<dim3(HID / 128, BT / 64), 256, 0, stream>>>(
        out2b, woutb, BT, HID, HID, d_out, nullptr, nullptr, nullptr);
}

// Round 5
// 405.920 us; speedup vs baseline: 1.0433x; 1.0433x over previous
//
#include <hip/hip_runtime.h>

typedef unsigned short u16;
typedef __bf16 bf16x8 __attribute__((ext_vector_type(8)));
typedef float f32x4 __attribute__((ext_vector_type(4)));
typedef unsigned short us8 __attribute__((ext_vector_type(8)));

#define BB 4
#define TT 4096
#define HID 1024
#define NH 16
#define HD 64
#define BT (BB*TT)          // 16384 rows
#define NCH 128             // chunks over T
#define LOG_NCH 7
#define CLEN (TT/NCH)       // 32

__device__ __forceinline__ float bf2f(u16 u) {
    return __uint_as_float(((unsigned)u) << 16);
}
__device__ __forceinline__ u16 f2bf(float f) {
    unsigned u = __float_as_uint(f);
    unsigned r = 0x7FFFu + ((u >> 16) & 1u);
    return (u16)((u + r) >> 16);
}
__device__ __forceinline__ float phi(float x) {      // elu(x)+1
    return x > 0.f ? x + 1.f : __expf(x);
}
__device__ __forceinline__ float sigmoidf(float x) {
    return 1.f / (1.f + __expf(-x));
}
__device__ __forceinline__ float4 u4_to_f4(ushort4 u) {
    return make_float4(bf2f(u.x), bf2f(u.y), bf2f(u.z), bf2f(u.w));
}

// ---------------- fused fp32 -> bf16 convert (one launch for all 4 tensors) ----------
#define CN1 (BT*HID/4)          // x      : 4194304
#define CN2 (3*HID*HID/4)       // Wqkv   :  786432
#define CN3 (HID*HID/4)         // Wgate  :  262144
#define CN4 (HID*HID/4)         // Wout   :  262144
__global__ void convert_all(const float4* __restrict__ x,    const float4* __restrict__ wqkv,
                            const float4* __restrict__ wgate, const float4* __restrict__ wout,
                            ushort4* __restrict__ xb,    ushort4* __restrict__ wqkvb,
                            ushort4* __restrict__ wgateb, ushort4* __restrict__ woutb) {
    int i = blockIdx.x * 256 + threadIdx.x;
    const float4* src; ushort4* dst; int j;
    if (i < CN1)                 { src = x;     dst = xb;     j = i; }
    else if (i < CN1+CN2)        { src = wqkv;  dst = wqkvb;  j = i - CN1; }
    else if (i < CN1+CN2+CN3)    { src = wgate; dst = wgateb; j = i - CN1 - CN2; }
    else                         { src = wout;  dst = woutb;  j = i - CN1 - CN2 - CN3; }
    float4 f = src[j];
    ushort4 u;
    u.x = f2bf(f.x); u.y = f2bf(f.y); u.z = f2bf(f.z); u.w = f2bf(f.w);
    dst[j] = u;
}

// ---------------- MFMA GEMM1: C[M,N] = A[M,K] @ W[N,K]^T -> bf16 ---------------------
// ROUND-3 VERIFIED FORM (121 us, 0 bank conflicts, VGPR 76). 128x128 tile, BK=64,
// 4 waves (each 64x64 via 4x4 of 16x16x32 mfma). XOR-swizzled LDS. Direct reg->global
// epilogue. NO XCD remap (round 4 showed it costs 25 us despite lower FETCH: we are
// latency-bound, and linear order already gives concurrent blocks a shared A row-band).
__global__ __launch_bounds__(256)
void gemm_bt(const u16* __restrict__ A, const u16* __restrict__ Bm,
             int M, int N, int K, u16* __restrict__ Cout)
{
    __shared__ u16 As[128 * 64];
    __shared__ u16 Bs[128 * 64];
    const int tid  = threadIdx.x;
    const int wave = tid >> 6;
    const int lane = tid & 63;
    const int m0 = blockIdx.y * 128;
    const int n0 = blockIdx.x * 128;
    const int mw = (wave & 1) * 64;
    const int nw = (wave >> 1) * 64;
    const int r16 = lane & 15;

    f32x4 acc[4][4];
    #pragma unroll
    for (int i = 0; i < 4; ++i)
        #pragma unroll
        for (int j = 0; j < 4; ++j)
            acc[i][j] = (f32x4){0.f, 0.f, 0.f, 0.f};

    for (int k0 = 0; k0 < K; k0 += 64) {
        #pragma unroll
        for (int i = 0; i < 4; ++i) {
            int s   = i * 4 + wave;          // segment 0..15 (wave-uniform)
            int idx = s * 64 + lane;         // linear 16B-chunk index
            int pr  = idx >> 3;
            int pc  = idx & 7;
            int lc  = pc ^ (pr & 7);         // XOR swizzle
            const u16* gA = A  + (size_t)(m0 + pr) * K + k0 + lc * 8;
            const u16* gB = Bm + (size_t)(n0 + pr) * K + k0 + lc * 8;
            __builtin_amdgcn_global_load_lds(
                (const __attribute__((address_space(1))) void*)gA,
                (__attribute__((address_space(3))) void*)&As[s * 512], 16, 0, 0);
            __builtin_amdgcn_global_load_lds(
                (const __attribute__((address_space(1))) void*)gB,
                (__attribute__((address_space(3))) void*)&Bs[s * 512], 16, 0, 0);
        }
        __syncthreads();
        #pragma unroll
        for (int s2 = 0; s2 < 2; ++s2) {
            const int lcq = s2 * 4 + (lane >> 4);
            const int pcq = lcq ^ (r16 & 7);
            bf16x8 af[4], bq[4];
            #pragma unroll
            for (int i = 0; i < 4; ++i)
                af[i] = *(const bf16x8*)&As[(mw + i * 16 + r16) * 64 + pcq * 8];
            #pragma unroll
            for (int j = 0; j < 4; ++j)
                bq[j] = *(const bf16x8*)&Bs[(nw + j * 16 + r16) * 64 + pcq * 8];
            #pragma unroll
            for (int i = 0; i < 4; ++i)
                #pragma unroll
                for (int j = 0; j < 4; ++j)
                    acc[i][j] = __builtin_amdgcn_mfma_f32_16x16x32_bf16(af[i], bq[j], acc[i][j], 0, 0, 0);
        }
        __syncthreads();
    }

    // direct epilogue: C/D layout col=lane&15, row=(lane>>4)*4+reg
    #pragma unroll
    for (int i = 0; i < 4; ++i) {
        int rowb = m0 + mw + i * 16 + (lane >> 4) * 4;
        #pragma unroll
        for (int j = 0; j < 4; ++j) {
            int col = n0 + nw + j * 16 + r16;
            #pragma unroll
            for (int r = 0; r < 4; ++r)
                Cout[(size_t)(rowb + r) * N + col] = f2bf(acc[i][j][r]);
        }
    }
}

// ---------------- small GEMM: 64x128 tile, BK=128 (for N=1024 GEMMs) ----------------
// 8 stages (vs 16), 32 MFMA/wave/stage = GEMM1's density. LDS 48 KB -> 3 blocks/CU.
// Epilogue: C-tile through LDS with stride 132 (pad: write 2-way = free, read clean),
// coalesced vector loads/stores. EPI 1: gate blend (bf16). EPI 2: fp32 out.
#define CS_LD 132
template<int EPI>
__global__ __launch_bounds__(256)
void gemm_bt_sm(const u16* __restrict__ A, const u16* __restrict__ Bm,
                int M, int N, int K, void* __restrict__ Cout,
                const float* __restrict__ bg,
                const u16* __restrict__ attn,
                const u16* __restrict__ qkv)
{
    __shared__ u16 As[64 * 128];    // 16 KB
    __shared__ u16 Bs[128 * 128];   // 32 KB
    const int tid  = threadIdx.x;
    const int wave = tid >> 6;
    const int lane = tid & 63;
    const int m0 = blockIdx.y * 64;
    const int n0 = blockIdx.x * 128;
    const int mw = (wave & 1) * 32;
    const int nw = (wave >> 1) * 64;
    const int r16 = lane & 15;
    const int q4  = (lane >> 4) * 4;

    f32x4 acc[2][4];
    #pragma unroll
    for (int i = 0; i < 2; ++i)
        #pragma unroll
        for (int j = 0; j < 4; ++j)
            acc[i][j] = (f32x4){0.f, 0.f, 0.f, 0.f};

    for (int k0 = 0; k0 < K; k0 += 128) {
        // B: 32 segments (128 rows x 16 chunks), A: 16 segments (64 rows x 16 chunks)
        #pragma unroll
        for (int i = 0; i < 8; ++i) {
            int s   = i * 4 + wave;
            int idx = s * 64 + lane;
            int pr  = idx >> 4;              // row (16 chunks per 128-col row)
            int pc  = idx & 15;
            int lc  = pc ^ (pr & 7);         // XOR swizzle (same bank math as GEMM1)
            const u16* gB = Bm + (size_t)(n0 + pr) * K + k0 + lc * 8;
            __builtin_amdgcn_global_load_lds(
                (const __attribute__((address_space(1))) void*)gB,
                (__attribute__((address_space(3))) void*)&Bs[s * 512], 16, 0, 0);
            if (i < 4) {
                const u16* gA = A + (size_t)(m0 + pr) * K + k0 + lc * 8;
                __builtin_amdgcn_global_load_lds(
                    (const __attribute__((address_space(1))) void*)gA,
                    (__attribute__((address_space(3))) void*)&As[s * 512], 16, 0, 0);
            }
        }
        __syncthreads();
        #pragma unroll
        for (int s2 = 0; s2 < 4; ++s2) {
            const int lcq = s2 * 4 + (lane >> 4);
            const int pcq = lcq ^ (r16 & 7);
            bf16x8 af[2], bq[4];
            #pragma unroll
            for (int i = 0; i < 2; ++i)
                af[i] = *(const bf16x8*)&As[(mw + i * 16 + r16) * 128 + pcq * 8];
            #pragma unroll
            for (int j = 0; j < 4; ++j)
                bq[j] = *(const bf16x8*)&Bs[(nw + j * 16 + r16) * 128 + pcq * 8];
            #pragma unroll
            for (int i = 0; i < 2; ++i)
                #pragma unroll
                for (int j = 0; j < 4; ++j)
                    acc[i][j] = __builtin_amdgcn_mfma_f32_16x16x32_bf16(af[i], bq[j], acc[i][j], 0, 0, 0);
        }
        __syncthreads();
    }

    // ---- epilogue: 2 slabs of 32 rows through LDS (stride 132), vector RMW ----
    float* Cs = (float*)Bs;                 // 32*132*4 = 16.9 KB, fits in Bs
    #pragma unroll
    for (int slab = 0; slab < 2; ++slab) {
        if ((wave & 1) == slab) {
            #pragma unroll
            for (int i = 0; i < 2; ++i) {
                #pragma unroll
                for (int j = 0; j < 4; ++j) {
                    int col = nw + j * 16 + r16;
                    #pragma unroll
                    for (int r = 0; r < 4; ++r)
                        Cs[(i * 16 + q4 + r) * CS_LD + col] = acc[i][j][r];
                }
            }
        }
        __syncthreads();
        #pragma unroll
        for (int s = 0; s < 2; ++s) {
            int g   = s * 256 + tid;
            int row = g >> 4;
            int cg  = g & 15;
            const float* cp = &Cs[row * CS_LD + cg * 8];
            size_t grow = (size_t)(m0 + slab * 32 + row);
            int gcol = n0 + cg * 8;
            if (EPI == 1) {
                us8 a8 = *(const us8*)&attn[grow * HID + gcol];
                us8 v8 = *(const us8*)&qkv[grow * (3 * HID) + 2 * HID + gcol];
                float4 b0 = *(const float4*)&bg[gcol];
                float4 b1 = *(const float4*)&bg[gcol + 4];
                float bb[8] = {b0.x, b0.y, b0.z, b0.w, b1.x, b1.y, b1.z, b1.w};
                us8 o;
                #pragma unroll
                for (int e = 0; e < 8; ++e) {
                    float gv = sigmoidf(cp[e] + bb[e]);
                    o[e] = f2bf(gv * bf2f(a8[e]) + (1.f - gv) * bf2f(v8[e]));
                }
                *(us8*)&((u16*)Cout)[grow * HID + gcol] = o;
            } else {
                float4 c0 = *(const float4*)cp;
                float4 c1 = *(const float4*)(cp + 4);
                float* op = &((float*)Cout)[grow * N + gcol];
                *(float4*)op = c0;
                *(float4*)(op + 4) = c1;
            }
        }
        __syncthreads();
    }
}

// ---------------- scan pass A: per-chunk local finals (vectorized x4) --------------
__global__ void scan_finals(const u16* __restrict__ qkv, const float* __restrict__ decay_param,
                            float* __restrict__ ckv, float* __restrict__ cks) {
    int g  = blockIdx.x * 16 + (threadIdx.x >> 4);    // ((b*NH+h)*NCH + c)
    int sl = threadIdx.x & 15;
    int c = g & (NCH - 1);
    int h = (g >> LOG_NCH) & (NH - 1);
    int b = g >> (LOG_NCH + 4);
    float decay = sigmoidf(decay_param[h]);
    const u16* kp = qkv + (size_t)(b * TT + c * CLEN) * (3 * HID) + HID + h * HD + sl * 4;
    float4 skv = make_float4(0.f, 0.f, 0.f, 0.f);
    float4 sks = make_float4(0.f, 0.f, 0.f, 0.f);
    for (int t = 0; t < CLEN; ++t) {
        float4 k = u4_to_f4(*(const ushort4*)kp);
        float4 v = u4_to_f4(*(const ushort4*)(kp + HID));
        k.x = phi(k.x); k.y = phi(k.y); k.z = phi(k.z); k.w = phi(k.w);
        skv.x = decay * skv.x + k.x * v.x;  skv.y = decay * skv.y + k.y * v.y;
        skv.z = decay * skv.z + k.z * v.z;  skv.w = decay * skv.w + k.w * v.w;
        sks.x = decay * sks.x + k.x;        sks.y = decay * sks.y + k.y;
        sks.z = decay * sks.z + k.z;        sks.w = decay * sks.w + k.w;
        kp += 3 * HID;
    }
    *(float4*)(ckv + (size_t)g * 64 + sl * 4) = skv;
    *(float4*)(cks + (size_t)g * 64 + sl * 4) = sks;
}

// ---------------- scan pass B: cross-chunk exclusive prefix (in place) -------------
__global__ void scan_prefix(float* __restrict__ ckv, float* __restrict__ cks,
                            const float* __restrict__ decay_param) {
    int bh = blockIdx.x;
    int h  = bh & (NH - 1);
    int lane = threadIdx.x;
    float decay = sigmoidf(decay_param[h]);
    float dC = powf(decay, (float)CLEN);
    float* pkv = ckv + (size_t)bh * NCH * 64 + lane;
    float* pks = cks + (size_t)bh * NCH * 64 + lane;
    float fkv = 0.f, fks = 0.f;
    for (int c = 0; c < NCH; ++c) {
        float lkv = pkv[c * 64], lks = pks[c * 64];
        pkv[c * 64] = fkv; pks[c * 64] = fks;
        fkv = fkv * dC + lkv;
        fks = fks * dC + lks;
    }
}

// ---------------- scan pass C: apply with init, den-reduce, write attn (x4) --------
__global__ void scan_apply(const u16* __restrict__ qkv, const float* __restrict__ decay_param,
                           const float* __restrict__ ckv, const float* __restrict__ cks,
                           u16* __restrict__ attn) {
    int g  = blockIdx.x * 16 + (threadIdx.x >> 4);
    int sl = threadIdx.x & 15;
    int c = g & (NCH - 1);
    int h = (g >> LOG_NCH) & (NH - 1);
    int b = g >> (LOG_NCH + 4);
    float decay = sigmoidf(decay_param[h]);
    float4 skv = *(const float4*)(ckv + (size_t)g * 64 + sl * 4);
    float4 sks = *(const float4*)(cks + (size_t)g * 64 + sl * 4);
    const u16* qp = qkv + (size_t)(b * TT + c * CLEN) * (3 * HID) + h * HD + sl * 4;
    u16* op = attn + (size_t)(b * TT + c * CLEN) * HID + h * HD + sl * 4;
    for (int t = 0; t < CLEN; ++t) {
        float4 q = u4_to_f4(*(const ushort4*)qp);
        float4 k = u4_to_f4(*(const ushort4*)(qp + HID));
        float4 v = u4_to_f4(*(const ushort4*)(qp + 2 * HID));
        q.x = phi(q.x); q.y = phi(q.y); q.z = phi(q.z); q.w = phi(q.w);
        k.x = phi(k.x); k.y = phi(k.y); k.z = phi(k.z); k.w = phi(k.w);
        skv.x = decay * skv.x + k.x * v.x;  skv.y = decay * skv.y + k.y * v.y;
        skv.z = decay * skv.z + k.z * v.z;  skv.w = decay * skv.w + k.w * v.w;
        sks.x = decay * sks.x + k.x;        sks.y = decay * sks.y + k.y;
        sks.z = decay * sks.z + k.z;        sks.w = decay * sks.w + k.w;
        float s = q.x * sks.x + q.y * sks.y + q.z * sks.z + q.w * sks.w;
        s += __shfl_xor(s, 8);
        s += __shfl_xor(s, 4);
        s += __shfl_xor(s, 2);
        s += __shfl_xor(s, 1);
        float inv = 1.f / fmaxf(s, 1e-6f);
        ushort4 o;
        o.x = f2bf(q.x * skv.x * inv); o.y = f2bf(q.y * skv.y * inv);
        o.z = f2bf(q.z * skv.z * inv); o.w = f2bf(q.w * skv.w * inv);
        *(ushort4*)op = o;
        qp += 3 * HID;
        op += HID;
    }
}

extern "C" void kernel_launch(void* const* d_in, const int* in_sizes, int n_in,
                              void* d_out, int out_size, void* d_ws, size_t ws_size,
                              hipStream_t stream) {
    const float* x     = (const float*)d_in[0];   // [4,4096,1024]
    const float* Wqkv  = (const float*)d_in[1];   // [3072,1024]
    const float* Wout  = (const float*)d_in[2];   // [1024,1024]
    const float* Wgate = (const float*)d_in[3];   // [1024,1024]
    const float* bgate = (const float*)d_in[4];   // [1024]
    const float* decay = (const float*)d_in[5];   // [16]

    // workspace layout (bf16 elements)
    u16* xb     = (u16*)d_ws;                                 // 16384*1024 (aliased as attn later)
    u16* wqkvb  = xb    + (size_t)BT * HID;                   // 3072*1024
    u16* wgateb = wqkvb + (size_t)3 * HID * HID;              // 1024*1024
    u16* woutb  = wgateb + (size_t)HID * HID;                 // 1024*1024
    u16* qkvb   = woutb + (size_t)HID * HID;                  // 16384*3072
    u16* out2b  = qkvb  + (size_t)BT * 3 * HID;               // 16384*1024
    float* ckv  = (float*)(out2b + (size_t)BT * HID);         // 4*16*128*64
    float* cks  = ckv + (size_t)BB * NH * NCH * HD;
    u16* attnb  = xb;  // alias: x dead after GEMM1

    // fused converts (one launch)
    convert_all<<<(CN1 + CN2 + CN3 + CN4) / 256, 256, 0, stream>>>(
        (const float4*)x, (const float4*)Wqkv, (const float4*)Wgate, (const float4*)Wout,
        (ushort4*)xb, (ushort4*)wqkvb, (ushort4*)wgateb, (ushort4*)woutb);

    // GEMM1: qkv = x @ Wqkv^T  -> bf16 [16384,3072]
    gemm_bt<<<dim3(3 * HID / 128, BT / 128), 256, 0, stream>>>(
        xb, wqkvb, BT, 3 * HID, HID, qkvb);

    // decay scans -> attn bf16 [16384,1024]
    scan_finals<<<BB * NH * NCH / 16, 256, 0, stream>>>(qkvb, decay, ckv, cks);
    scan_prefix<<<BB * NH, 64, 0, stream>>>(ckv, cks, decay);
    scan_apply<<<BB * NH * NCH / 16, 256, 0, stream>>>(qkvb, decay, ckv, cks, attnb);

    // GEMM2: gate + blend -> out2 bf16 [16384,1024]  (BK=128 small tile)
    gemm_bt_sm<1><<<dim3(HID / 128, BT / 64), 256, 0, stream>>>(
        attnb, wgateb, BT, HID, HID, out2b, bgate, attnb, qkvb);

    // GEMM3: final projection -> fp32 d_out  (BK=128 small tile)
    gemm_bt_sm<2><<<dim3(HID / 128, BT / 64), 256, 0, stream>>>(
        out2b, woutb, BT, HID, HID, d_out, nullptr, nullptr, nullptr);
}

// Round 6
// 403.196 us; speedup vs baseline: 1.0503x; 1.0068x over previous
//
#include <hip/hip_runtime.h>

typedef unsigned short u16;
typedef __bf16 bf16x8 __attribute__((ext_vector_type(8)));
typedef float f32x4 __attribute__((ext_vector_type(4)));

#define BB 4
#define TT 4096
#define HID 1024
#define NH 16
#define HD 64
#define BT (BB*TT)          // 16384 rows
#define NCH 128             // chunks over T
#define LOG_NCH 7
#define CLEN (TT/NCH)       // 32

__device__ __forceinline__ float bf2f(u16 u) {
    return __uint_as_float(((unsigned)u) << 16);
}
__device__ __forceinline__ u16 f2bf(float f) {
    unsigned u = __float_as_uint(f);
    unsigned r = 0x7FFFu + ((u >> 16) & 1u);
    return (u16)((u + r) >> 16);
}
__device__ __forceinline__ float phi(float x) {      // elu(x)+1
    return x > 0.f ? x + 1.f : __expf(x);
}
__device__ __forceinline__ float sigmoidf(float x) {
    return 1.f / (1.f + __expf(-x));
}
__device__ __forceinline__ float4 u4_to_f4(ushort4 u) {
    return make_float4(bf2f(u.x), bf2f(u.y), bf2f(u.z), bf2f(u.w));
}

// ---------------- fused fp32 -> bf16 convert (one launch for all 4 tensors) ----------
#define CN1 (BT*HID/4)          // x      : 4194304
#define CN2 (3*HID*HID/4)       // Wqkv   :  786432
#define CN3 (HID*HID/4)         // Wgate  :  262144
#define CN4 (HID*HID/4)         // Wout   :  262144
__global__ void convert_all(const float4* __restrict__ x,    const float4* __restrict__ wqkv,
                            const float4* __restrict__ wgate, const float4* __restrict__ wout,
                            ushort4* __restrict__ xb,    ushort4* __restrict__ wqkvb,
                            ushort4* __restrict__ wgateb, ushort4* __restrict__ woutb) {
    int i = blockIdx.x * 256 + threadIdx.x;
    const float4* src; ushort4* dst; int j;
    if (i < CN1)                 { src = x;     dst = xb;     j = i; }
    else if (i < CN1+CN2)        { src = wqkv;  dst = wqkvb;  j = i - CN1; }
    else if (i < CN1+CN2+CN3)    { src = wgate; dst = wgateb; j = i - CN1 - CN2; }
    else                         { src = wout;  dst = woutb;  j = i - CN1 - CN2 - CN3; }
    float4 f = src[j];
    ushort4 u;
    u.x = f2bf(f.x); u.y = f2bf(f.y); u.z = f2bf(f.z); u.w = f2bf(f.w);
    dst[j] = u;
}

// ---------------- MFMA GEMM1: C[M,N] = A[M,K] @ W[N,K]^T -> bf16 ---------------------
// Round-3 structure (128x128, BK=64, XOR swizzle, direct epilogue) + hoisted
// addressing: global staging pointers precomputed and bumped (+64 elems/stage),
// swizzled LDS read bases precomputed (loop-invariant, ds_read gets const offsets).
__global__ __launch_bounds__(256)
void gemm_bt(const u16* __restrict__ A, const u16* __restrict__ Bm,
             int M, int N, int K, u16* __restrict__ Cout)
{
    __shared__ u16 As[128 * 64];
    __shared__ u16 Bs[128 * 64];
    const int tid  = threadIdx.x;
    const int wave = tid >> 6;
    const int lane = tid & 63;
    const int m0 = blockIdx.y * 128;
    const int n0 = blockIdx.x * 128;
    const int mw = (wave & 1) * 64;
    const int nw = (wave >> 1) * 64;
    const int r16 = lane & 15;

    // --- hoisted staging pointers (global) and LDS dests ---
    const u16* pA[4];
    const u16* pB[4];
    u16* dA[4];
    u16* dB[4];
    #pragma unroll
    for (int i = 0; i < 4; ++i) {
        int s   = i * 4 + wave;          // segment 0..15 (wave-uniform)
        int idx = s * 64 + lane;         // linear 16B-chunk index
        int pr  = idx >> 3;
        int pc  = idx & 7;
        int lc  = pc ^ (pr & 7);         // XOR swizzle
        pA[i] = A  + (size_t)(m0 + pr) * K + lc * 8;
        pB[i] = Bm + (size_t)(n0 + pr) * K + lc * 8;
        dA[i] = &As[s * 512];
        dB[i] = &Bs[s * 512];
    }
    // --- hoisted swizzled LDS read bases (s2 = 0,1) ---
    const int pcq0 = ((lane >> 4)    ) ^ (r16 & 7);
    const int pcq1 = ((lane >> 4) + 4) ^ (r16 & 7);
    const u16* aB[2] = { &As[(mw + r16) * 64 + pcq0 * 8], &As[(mw + r16) * 64 + pcq1 * 8] };
    const u16* bB[2] = { &Bs[(nw + r16) * 64 + pcq0 * 8], &Bs[(nw + r16) * 64 + pcq1 * 8] };

    f32x4 acc[4][4];
    #pragma unroll
    for (int i = 0; i < 4; ++i)
        #pragma unroll
        for (int j = 0; j < 4; ++j)
            acc[i][j] = (f32x4){0.f, 0.f, 0.f, 0.f};

    for (int k0 = 0; k0 < K; k0 += 64) {
        #pragma unroll
        for (int i = 0; i < 4; ++i) {
            __builtin_amdgcn_global_load_lds(
                (const __attribute__((address_space(1))) void*)pA[i],
                (__attribute__((address_space(3))) void*)dA[i], 16, 0, 0);
            __builtin_amdgcn_global_load_lds(
                (const __attribute__((address_space(1))) void*)pB[i],
                (__attribute__((address_space(3))) void*)dB[i], 16, 0, 0);
            pA[i] += 64;
            pB[i] += 64;
        }
        __syncthreads();
        #pragma unroll
        for (int s2 = 0; s2 < 2; ++s2) {
            bf16x8 af[4], bq[4];
            #pragma unroll
            for (int i = 0; i < 4; ++i)
                af[i] = *(const bf16x8*)(aB[s2] + i * 1024);   // +i*16 rows (const offset)
            #pragma unroll
            for (int j = 0; j < 4; ++j)
                bq[j] = *(const bf16x8*)(bB[s2] + j * 1024);
            #pragma unroll
            for (int i = 0; i < 4; ++i)
                #pragma unroll
                for (int j = 0; j < 4; ++j)
                    acc[i][j] = __builtin_amdgcn_mfma_f32_16x16x32_bf16(af[i], bq[j], acc[i][j], 0, 0, 0);
        }
        __syncthreads();
    }

    // direct epilogue: C/D layout col=lane&15, row=(lane>>4)*4+reg
    #pragma unroll
    for (int i = 0; i < 4; ++i) {
        int rowb = m0 + mw + i * 16 + (lane >> 4) * 4;
        #pragma unroll
        for (int j = 0; j < 4; ++j) {
            int col = n0 + nw + j * 16 + r16;
            #pragma unroll
            for (int r = 0; r < 4; ++r)
                Cout[(size_t)(rowb + r) * N + col] = f2bf(acc[i][j][r]);
        }
    }
}

// ---------------- small GEMM: 64x128 tile, BK=64 (round-3 form) + hoisting ----------
// 24 KB LDS -> 6 blocks/CU resident (occupancy beats barrier-amortization here:
// BK=128/48KB variant measured +7 us). EPI 1: gate blend (bf16). EPI 2: fp32 out.
template<int EPI>
__global__ __launch_bounds__(256)
void gemm_bt_sm(const u16* __restrict__ A, const u16* __restrict__ Bm,
                int M, int N, int K, void* __restrict__ Cout,
                const float* __restrict__ bg,
                const u16* __restrict__ attn,
                const u16* __restrict__ qkv)
{
    __shared__ u16 As[64 * 64];
    __shared__ u16 Bs[128 * 64];
    const int tid  = threadIdx.x;
    const int wave = tid >> 6;
    const int lane = tid & 63;
    const int m0 = blockIdx.y * 64;
    const int n0 = blockIdx.x * 128;
    const int mw = (wave & 1) * 32;
    const int nw = (wave >> 1) * 64;
    const int r16 = lane & 15;

    // --- hoisted staging pointers ---
    const u16* pB[4];
    u16* dB[4];
    const u16* pA[2];
    u16* dA[2];
    #pragma unroll
    for (int i = 0; i < 4; ++i) {
        int s   = i * 4 + wave;
        int idx = s * 64 + lane;
        int pr  = idx >> 3;
        int pc  = idx & 7;
        int lc  = pc ^ (pr & 7);
        pB[i] = Bm + (size_t)(n0 + pr) * K + lc * 8;
        dB[i] = &Bs[s * 512];
        if (i < 2) {
            pA[i] = A + (size_t)(m0 + pr) * K + lc * 8;
            dA[i] = &As[s * 512];
        }
    }
    const int pcq0 = ((lane >> 4)    ) ^ (r16 & 7);
    const int pcq1 = ((lane >> 4) + 4) ^ (r16 & 7);
    const u16* aB[2] = { &As[(mw + r16) * 64 + pcq0 * 8], &As[(mw + r16) * 64 + pcq1 * 8] };
    const u16* bB[2] = { &Bs[(nw + r16) * 64 + pcq0 * 8], &Bs[(nw + r16) * 64 + pcq1 * 8] };

    f32x4 acc[2][4];
    #pragma unroll
    for (int i = 0; i < 2; ++i)
        #pragma unroll
        for (int j = 0; j < 4; ++j)
            acc[i][j] = (f32x4){0.f, 0.f, 0.f, 0.f};

    for (int k0 = 0; k0 < K; k0 += 64) {
        #pragma unroll
        for (int i = 0; i < 4; ++i) {
            __builtin_amdgcn_global_load_lds(
                (const __attribute__((address_space(1))) void*)pB[i],
                (__attribute__((address_space(3))) void*)dB[i], 16, 0, 0);
            pB[i] += 64;
            if (i < 2) {
                __builtin_amdgcn_global_load_lds(
                    (const __attribute__((address_space(1))) void*)pA[i],
                    (__attribute__((address_space(3))) void*)dA[i], 16, 0, 0);
                pA[i] += 64;
            }
        }
        __syncthreads();
        #pragma unroll
        for (int s2 = 0; s2 < 2; ++s2) {
            bf16x8 af[2], bq[4];
            #pragma unroll
            for (int i = 0; i < 2; ++i)
                af[i] = *(const bf16x8*)(aB[s2] + i * 1024);
            #pragma unroll
            for (int j = 0; j < 4; ++j)
                bq[j] = *(const bf16x8*)(bB[s2] + j * 1024);
            #pragma unroll
            for (int i = 0; i < 2; ++i)
                #pragma unroll
                for (int j = 0; j < 4; ++j)
                    acc[i][j] = __builtin_amdgcn_mfma_f32_16x16x32_bf16(af[i], bq[j], acc[i][j], 0, 0, 0);
        }
        __syncthreads();
    }

    // direct epilogue (round-3 form)
    #pragma unroll
    for (int i = 0; i < 2; ++i) {
        int rowb = m0 + mw + i * 16 + (lane >> 4) * 4;
        #pragma unroll
        for (int j = 0; j < 4; ++j) {
            int col = n0 + nw + j * 16 + r16;
            #pragma unroll
            for (int r = 0; r < 4; ++r) {
                float v = acc[i][j][r];
                size_t row = (size_t)(rowb + r);
                if (EPI == 1) {
                    float g  = sigmoidf(v + bg[col]);
                    float at = bf2f(attn[row * HID + col]);
                    float vd = bf2f(qkv[row * (3 * HID) + 2 * HID + col]);
                    ((u16*)Cout)[row * HID + col] = f2bf(g * at + (1.f - g) * vd);
                } else {
                    ((float*)Cout)[row * N + col] = v;
                }
            }
        }
    }
}

// ---------------- scan pass A: per-chunk local finals (vectorized x4) --------------
__global__ void scan_finals(const u16* __restrict__ qkv, const float* __restrict__ decay_param,
                            float* __restrict__ ckv, float* __restrict__ cks) {
    int g  = blockIdx.x * 16 + (threadIdx.x >> 4);    // ((b*NH+h)*NCH + c)
    int sl = threadIdx.x & 15;
    int c = g & (NCH - 1);
    int h = (g >> LOG_NCH) & (NH - 1);
    int b = g >> (LOG_NCH + 4);
    float decay = sigmoidf(decay_param[h]);
    const u16* kp = qkv + (size_t)(b * TT + c * CLEN) * (3 * HID) + HID + h * HD + sl * 4;
    float4 skv = make_float4(0.f, 0.f, 0.f, 0.f);
    float4 sks = make_float4(0.f, 0.f, 0.f, 0.f);
    for (int t = 0; t < CLEN; ++t) {
        float4 k = u4_to_f4(*(const ushort4*)kp);
        float4 v = u4_to_f4(*(const ushort4*)(kp + HID));
        k.x = phi(k.x); k.y = phi(k.y); k.z = phi(k.z); k.w = phi(k.w);
        skv.x = decay * skv.x + k.x * v.x;  skv.y = decay * skv.y + k.y * v.y;
        skv.z = decay * skv.z + k.z * v.z;  skv.w = decay * skv.w + k.w * v.w;
        sks.x = decay * sks.x + k.x;        sks.y = decay * sks.y + k.y;
        sks.z = decay * sks.z + k.z;        sks.w = decay * sks.w + k.w;
        kp += 3 * HID;
    }
    *(float4*)(ckv + (size_t)g * 64 + sl * 4) = skv;
    *(float4*)(cks + (size_t)g * 64 + sl * 4) = sks;
}

// ---------------- scan pass B: cross-chunk exclusive prefix (in place) -------------
__global__ void scan_prefix(float* __restrict__ ckv, float* __restrict__ cks,
                            const float* __restrict__ decay_param) {
    int bh = blockIdx.x;
    int h  = bh & (NH - 1);
    int lane = threadIdx.x;
    float decay = sigmoidf(decay_param[h]);
    float dC = powf(decay, (float)CLEN);
    float* pkv = ckv + (size_t)bh * NCH * 64 + lane;
    float* pks = cks + (size_t)bh * NCH * 64 + lane;
    float fkv = 0.f, fks = 0.f;
    for (int c = 0; c < NCH; ++c) {
        float lkv = pkv[c * 64], lks = pks[c * 64];
        pkv[c * 64] = fkv; pks[c * 64] = fks;
        fkv = fkv * dC + lkv;
        fks = fks * dC + lks;
    }
}

// ---------------- scan pass C: apply with init, den-reduce, write attn (x4) --------
__global__ void scan_apply(const u16* __restrict__ qkv, const float* __restrict__ decay_param,
                           const float* __restrict__ ckv, const float* __restrict__ cks,
                           u16* __restrict__ attn) {
    int g  = blockIdx.x * 16 + (threadIdx.x >> 4);
    int sl = threadIdx.x & 15;
    int c = g & (NCH - 1);
    int h = (g >> LOG_NCH) & (NH - 1);
    int b = g >> (LOG_NCH + 4);
    float decay = sigmoidf(decay_param[h]);
    float4 skv = *(const float4*)(ckv + (size_t)g * 64 + sl * 4);
    float4 sks = *(const float4*)(cks + (size_t)g * 64 + sl * 4);
    const u16* qp = qkv + (size_t)(b * TT + c * CLEN) * (3 * HID) + h * HD + sl * 4;
    u16* op = attn + (size_t)(b * TT + c * CLEN) * HID + h * HD + sl * 4;
    for (int t = 0; t < CLEN; ++t) {
        float4 q = u4_to_f4(*(const ushort4*)qp);
        float4 k = u4_to_f4(*(const ushort4*)(qp + HID));
        float4 v = u4_to_f4(*(const ushort4*)(qp + 2 * HID));
        q.x = phi(q.x); q.y = phi(q.y); q.z = phi(q.z); q.w = phi(q.w);
        k.x = phi(k.x); k.y = phi(k.y); k.z = phi(k.z); k.w = phi(k.w);
        skv.x = decay * skv.x + k.x * v.x;  skv.y = decay * skv.y + k.y * v.y;
        skv.z = decay * skv.z + k.z * v.z;  skv.w = decay * skv.w + k.w * v.w;
        sks.x = decay * sks.x + k.x;        sks.y = decay * sks.y + k.y;
        sks.z = decay * sks.z + k.z;        sks.w = decay * sks.w + k.w;
        float s = q.x * sks.x + q.y * sks.y + q.z * sks.z + q.w * sks.w;
        s += __shfl_xor(s, 8);
        s += __shfl_xor(s, 4);
        s += __shfl_xor(s, 2);
        s += __shfl_xor(s, 1);
        float inv = 1.f / fmaxf(s, 1e-6f);
        ushort4 o;
        o.x = f2bf(q.x * skv.x * inv); o.y = f2bf(q.y * skv.y * inv);
        o.z = f2bf(q.z * skv.z * inv); o.w = f2bf(q.w * skv.w * inv);
        *(ushort4*)op = o;
        qp += 3 * HID;
        op += HID;
    }
}

extern "C" void kernel_launch(void* const* d_in, const int* in_sizes, int n_in,
                              void* d_out, int out_size, void* d_ws, size_t ws_size,
                              hipStream_t stream) {
    const float* x     = (const float*)d_in[0];   // [4,4096,1024]
    const float* Wqkv  = (const float*)d_in[1];   // [3072,1024]
    const float* Wout  = (const float*)d_in[2];   // [1024,1024]
    const float* Wgate = (const float*)d_in[3];   // [1024,1024]
    const float* bgate = (const float*)d_in[4];   // [1024]
    const float* decay = (const float*)d_in[5];   // [16]

    // workspace layout (bf16 elements)
    u16* xb     = (u16*)d_ws;                                 // 16384*1024 (aliased as attn later)
    u16* wqkvb  = xb    + (size_t)BT * HID;                   // 3072*1024
    u16* wgateb = wqkvb + (size_t)3 * HID * HID;              // 1024*1024
    u16* woutb  = wgateb + (size_t)HID * HID;                 // 1024*1024
    u16* qkvb   = woutb + (size_t)HID * HID;                  // 16384*3072
    u16* out2b  = qkvb  + (size_t)BT * 3 * HID;               // 16384*1024
    float* ckv  = (float*)(out2b + (size_t)BT * HID);         // 4*16*128*64
    float* cks  = ckv + (size_t)BB * NH * NCH * HD;
    u16* attnb  = xb;  // alias: x dead after GEMM1

    // fused converts (one launch)
    convert_all<<<(CN1 + CN2 + CN3 + CN4) / 256, 256, 0, stream>>>(
        (const float4*)x, (const float4*)Wqkv, (const float4*)Wgate, (const float4*)Wout,
        (ushort4*)xb, (ushort4*)wqkvb, (ushort4*)wgateb, (ushort4*)woutb);

    // GEMM1: qkv = x @ Wqkv^T  -> bf16 [16384,3072]
    gemm_bt<<<dim3(3 * HID / 128, BT / 128), 256, 0, stream>>>(
        xb, wqkvb, BT, 3 * HID, HID, qkvb);

    // decay scans -> attn bf16 [16384,1024]
    scan_finals<<<BB * NH * NCH / 16, 256, 0, stream>>>(qkvb, decay, ckv, cks);
    scan_prefix<<<BB * NH, 64, 0, stream>>>(ckv, cks, decay);
    scan_apply<<<BB * NH * NCH / 16, 256, 0, stream>>>(qkvb, decay, ckv, cks, attnb);

    // GEMM2: gate + blend -> out2 bf16 [16384,1024]
    gemm_bt_sm<1><<<dim3(HID / 128, BT / 64), 256, 0, stream>>>(
        attnb, wgateb, BT, HID, HID, out2b, bgate, attnb, qkvb);

    // GEMM3: final projection -> fp32 d_out
    gemm_bt_sm<2><<<dim3(HID / 128, BT / 64), 256, 0, stream>>>(
        out2b, woutb, BT, HID, HID, d_out, nullptr, nullptr, nullptr);
}